// Round 2
// baseline (10123.638 us; speedup 1.0000x reference)
//
#include <hip/hip_runtime.h>
#include <hip/hip_bf16.h>
#include <math.h>

// B=8, S=128; D=512; H=8, HD=64; L=2; steps=20 (fixed).
// 8 groups (=batches) x 16 blocks. 4 phases/iter. K-loops pipelined with
// s_waitcnt vmcnt(N) + raw s_barrier (DMA stays in flight across barriers);
// B/C/D use a 3-deep LDS ring; first stages prefetched inside the group
// barrier (weights are read-only -> safe).
//
// R1/R2: cache-op-free group barriers. The R0 barriers used agent
// release/acquire fences (buffer_wbl2 + L2 invalidate = two L2 tag-walks per
// barrier, 8/iter) which flushed ~1.7MB dirty per group-phase (matches
// WRITE_SIZE=568MB) and evicted all read-only data. Now all inter-phase
// tensors (h, ob*, ff*, ln-stats, hm) go through the LLC with sc0 sc1
// write-through stores / read-through loads (correct for ANY block->XCD
// mapping), and the barrier is just per-wave vmcnt(0) drain + relaxed atomic.
// Only the one-time init barrier keeps full release/acquire.
//
// R2 hardening (R1 had two register hazards from compiler-invisible loads):
//  (a) pipelined loops are manually 2x-unrolled with named even/odd register
//      sets -> NO copy of in-flight load destinations exists anywhere;
//  (b) sched_barrier(0) after every manual s_waitcnt and raw s_barrier so
//      register-only MFMA/VALU cannot hoist above a wait or sink past a
//      barrier (cdna rule #18).
#define NTOK 1024
#define DM   512
#define NB   128

typedef unsigned short u16;
typedef __attribute__((ext_vector_type(8))) short short8;
typedef __attribute__((ext_vector_type(4))) float f32x4;
typedef __attribute__((ext_vector_type(2))) float f32x2;
typedef __attribute__((address_space(1))) const void* as1cv;
typedef __attribute__((address_space(3))) void* as3v;

// s_waitcnt imms (gfx9): vmcnt[3:0]|[15:14], expcnt=7<<4, lgkm=15<<8
#define VM12 0x0F7C
#define VM20 0x4F74
#define VM0  0x0F70
#define VM8  0x0F78
#define VM16 0x4F70

#define WAITB(imm) do { __builtin_amdgcn_s_waitcnt(imm); \
                        __builtin_amdgcn_sched_barrier(0); } while (0)
#define BARB()     do { __builtin_amdgcn_s_barrier(); \
                        __builtin_amdgcn_sched_barrier(0); } while (0)

__device__ inline u16 f2bf(float f) {
  __hip_bfloat16 h = __float2bfloat16(f);
  return *reinterpret_cast<u16*>(&h);
}
__device__ inline float bf2f(u16 b) {
  union { unsigned u; float f; } x; x.u = (unsigned)b << 16; return x.f;
}
__device__ inline void split8(const float* v, short8& hi, short8& lo) {
#pragma unroll
  for (int j = 0; j < 8; j++) {
    u16 h = f2bf(v[j]);
    hi[j] = (short)h;
    lo[j] = (short)f2bf(v[j] - bf2f(h));
  }
}
__device__ __forceinline__ f32x4 MFMA(short8 a, short8 b, f32x4 c) {
  return __builtin_amdgcn_mfma_f32_16x16x32_bf16(a, b, c, 0, 0, 0);
}
__device__ __forceinline__ void atomAddF(float* p, float v) {
  __hip_atomic_fetch_add(p, v, __ATOMIC_RELAXED, __HIP_MEMORY_SCOPE_AGENT);
}

// ---- sc0 sc1 (LLC-coherent) and cached inline-asm memory ops -------------
// Invisible to compiler waitcnt tracking: every use is covered by the manual
// VM* pipeline waits or vmwait0(), and uses are fenced by sched_barrier(0).
__device__ __forceinline__ f32x4 ldg_cs4(const float* p) {
  f32x4 r;
  asm volatile("global_load_dwordx4 %0, %1, off sc0 sc1" : "=v"(r) : "v"(p) : "memory");
  return r;
}
__device__ __forceinline__ f32x2 ldg_cs2(const float* p) {
  f32x2 r;
  asm volatile("global_load_dwordx2 %0, %1, off sc0 sc1" : "=v"(r) : "v"(p) : "memory");
  return r;
}
__device__ __forceinline__ float ldg_cs1(const float* p) {
  float r;
  asm volatile("global_load_dword %0, %1, off sc0 sc1" : "=v"(r) : "v"(p) : "memory");
  return r;
}
__device__ __forceinline__ short8 ldg_cs_s8(const u16* p) {
  short8 r;
  asm volatile("global_load_dwordx4 %0, %1, off sc0 sc1" : "=v"(r) : "v"(p) : "memory");
  return r;
}
__device__ __forceinline__ f32x4 ldg_nrm4(const float* p) {   // cached, hidden from compiler
  f32x4 r;
  asm volatile("global_load_dwordx4 %0, %1, off" : "=v"(r) : "v"(p) : "memory");
  return r;
}
__device__ __forceinline__ float ldg_nrm1(const float* p) {
  float r;
  asm volatile("global_load_dword %0, %1, off" : "=v"(r) : "v"(p) : "memory");
  return r;
}
__device__ __forceinline__ void stg_cs1(float* p, float v) {
  asm volatile("global_store_dword %0, %1, off sc0 sc1" :: "v"(p), "v"(v) : "memory");
}
__device__ __forceinline__ void stg_cs_u16(u16* p, u16 v) {
  unsigned w = v;
  asm volatile("global_store_short %0, %1, off sc0 sc1" :: "v"(p), "v"(w) : "memory");
}
__device__ __forceinline__ void vmwait0() {
  asm volatile("s_waitcnt vmcnt(0)" ::: "memory");
  __builtin_amdgcn_sched_barrier(0);
}

enum { EP_RESID = 1, EP_TANHLERP = 3 };

struct KArgs {
  const int* x;
  const float* tok; const float* pos;
  const float* W[6];
  const float* bias6[6];
  const float* ln1g; const float* ln1b; const float* ln2g; const float* ln2b;
  const float* hw; const float* hb;
  float* out;
  float* xe; float* h;
  u16* obh; u16* obl;
  u16* ffh; u16* ffl;
  u16* vT;
  float* hm;
  u16* WTh[6]; u16* WTl[6];
  float* ln1sum; float* ln2sum;
  unsigned* bar;
};

#define SMEM_BYTES 49152

// ---- strong barrier (init only): full release/acquire --------------------
__device__ __forceinline__ void bar_arrive(unsigned* ctr, int tid) {
  __syncthreads();
  if (tid == 0)
    __hip_atomic_fetch_add(ctr, 1u, __ATOMIC_RELEASE, __HIP_MEMORY_SCOPE_AGENT);
}
__device__ __forceinline__ void bar_wait(unsigned* ctr, unsigned target, int tid) {
  if (tid == 0) {
    while (__hip_atomic_load(ctr, __ATOMIC_RELAXED, __HIP_MEMORY_SCOPE_AGENT) < target)
      __builtin_amdgcn_s_sleep(2);
    __builtin_amdgcn_fence(__ATOMIC_ACQUIRE, "agent");
  }
  __syncthreads();
}
// ---- weak barrier (steady-state loop): no cache maintenance ops ----------
__device__ __forceinline__ void bar_arrive_weak(unsigned* ctr, int tid) {
  asm volatile("s_waitcnt vmcnt(0)" ::: "memory");  // drain this wave's sc stores
  __syncthreads();
  if (tid == 0)
    __hip_atomic_fetch_add(ctr, 1u, __ATOMIC_RELAXED, __HIP_MEMORY_SCOPE_AGENT);
}
__device__ __forceinline__ void bar_wait_weak(unsigned* ctr, unsigned target, int tid) {
  if (tid == 0) {
    while (__hip_atomic_load(ctr, __ATOMIC_RELAXED, __HIP_MEMORY_SCOPE_AGENT) < target)
      __builtin_amdgcn_s_sleep(2);
  }
  asm volatile("s_waitcnt vmcnt(0)" ::: "memory");  // drain this block's prefetch DMAs
  __syncthreads();
}
__global__ void bar_init(unsigned* bar) { bar[threadIdx.x] = 0u; bar[256 + threadIdx.x] = 0u; }

// ---------------- DMA helpers (XOR swizzle; verified r9) ----------------
__device__ __forceinline__ void dmaW64(const u16* gbase, int K, int k0, u16* lds, int tid) {
  const int wave = tid >> 6, lane = tid & 63;
#pragma unroll
  for (int i = 0; i < 2; i++) {
    const int lc = wave * 128 + i * 64 + lane;
    const int n = lc >> 3, sl = lc & 7;
    const int c = sl ^ (n & 7);
    const u16* g = gbase + (size_t)n * K + k0 + c * 8;
    u16* dst = lds + (size_t)(wave * 128 + i * 64) * 8;
    __builtin_amdgcn_global_load_lds((as1cv)(const void*)g, (as3v)(void*)dst, 16, 0, 0);
  }
}
__device__ __forceinline__ int boff64(int n, int cp) { return n * 64 + ((cp ^ (n & 7)) << 3); }

__device__ __forceinline__ void dmaW32(const u16* gbase, int K, int k0, u16* lds, int tid) {
  const int wave = tid >> 6, lane = tid & 63;
  const int lc = wave * 64 + lane;
  const int p = lc >> 3, s3 = lc & 7;
  const int c3 = s3 ^ (p & 7);
  const int n = p * 2 + (c3 >> 2);
  const int c = c3 & 3;
  const u16* g = gbase + (size_t)n * K + k0 + c * 8;
  u16* dst = lds + (size_t)(wave * 64) * 8;
  __builtin_amdgcn_global_load_lds((as1cv)(const void*)g, (as3v)(void*)dst, 16, 0, 0);
}
__device__ __forceinline__ int boff32(int n, int cq) {
  const int c3 = ((n & 1) << 2) | cq;
  return ((n >> 1) << 6) + ((c3 ^ ((n >> 1) & 7)) << 3);
}

// prefetches (issued between bar_arrive and bar_wait)
__device__ __forceinline__ void pfBD2(const u16* bh0, const u16* bl0, int K, char* sm, int tid) {
  dmaW64(bh0, K, 0,  (u16*)sm, tid);
  dmaW64(bl0, K, 0,  (u16*)sm + 4096, tid);
  dmaW64(bh0, K, 64, (u16*)(sm + 16384), tid);
  dmaW64(bl0, K, 64, (u16*)(sm + 16384) + 4096, tid);
}
__device__ __forceinline__ void pfA(const KArgs& a, int l, int head, char* sm, int tid) {
  const size_t o = (size_t)l * 512 * 512 + (size_t)head * 64 * 512;
  const u16* wz[6] = { a.WTh[0] + o, a.WTl[0] + o, a.WTh[1] + o,
                       a.WTl[1] + o, a.WTh[2] + o, a.WTl[2] + o };
#pragma unroll
  for (int z = 0; z < 6; z++) dmaW32(wz[z], 512, 0, (u16*)sm + z * 2048, tid);
}

// ---------------------------------------------------------------------------
// phaseA pipeline step (ks is a compile-time constant via full unroll).
// cur set: loads retired by this step's wait. nxt set: issued here, in flight.
// ---------------------------------------------------------------------------
__device__ __forceinline__ void stepA(
    int ks, const float* hR, const float* lg, const float* lb,
    const u16* const (&wz)[6], u16* const (&buf)[2], int tid, int q, int r16, int wn,
    const int (&RB)[4], const float (&mu)[4], const float (&iv)[4],
    f32x4 (&cA)[4][2], f32x4 (&cg)[2], f32x4 (&cbv)[2],
    f32x4 (&nA)[4][2], f32x4 (&ng)[2], f32x4 (&nbv)[2],
    f32x4 (&aq)[4][2], f32x4 (&ak)[4][2], f32x4 (&av)[4][2])
{
  if (ks + 1 < 16) {                  // A(ks+1): 12 vm-insts into nxt set
    const int kb = (ks + 1) * 32 + q * 8;
#pragma unroll
    for (int fi = 0; fi < 4; fi++) {
      const float* hp = hR + (size_t)(RB[fi] + r16) * DM + kb;
      nA[fi][0] = ldg_cs4(hp); nA[fi][1] = ldg_cs4(hp + 4);
    }
    ng[0] = ldg_nrm4(lg + kb); ng[1] = ldg_nrm4(lg + kb + 4);
    nbv[0] = ldg_nrm4(lb + kb); nbv[1] = ldg_nrm4(lb + kb + 4);
    WAITB(VM12);                      // retires A(ks)+DMA(ks); A(ks+1) in flight
  } else {
    WAITB(VM0);
  }
  BARB();
  if (ks + 1 < 16) {                  // DMA(ks+1) -> other buf
    u16* nbuf = buf[(ks + 1) & 1];
#pragma unroll
    for (int z2 = 0; z2 < 6; z2++) dmaW32(wz[z2], 512, (ks + 1) * 32, nbuf + z2 * 2048, tid);
  }
  const u16* cbuf = buf[ks & 1];
  short8 ah[4], al[4];
#pragma unroll
  for (int fi = 0; fi < 4; fi++) {
    float v[8] = {
      (cA[fi][0].x - mu[fi]) * iv[fi] * cg[0].x + cbv[0].x,
      (cA[fi][0].y - mu[fi]) * iv[fi] * cg[0].y + cbv[0].y,
      (cA[fi][0].z - mu[fi]) * iv[fi] * cg[0].z + cbv[0].z,
      (cA[fi][0].w - mu[fi]) * iv[fi] * cg[0].w + cbv[0].w,
      (cA[fi][1].x - mu[fi]) * iv[fi] * cg[1].x + cbv[1].x,
      (cA[fi][1].y - mu[fi]) * iv[fi] * cg[1].y + cbv[1].y,
      (cA[fi][1].z - mu[fi]) * iv[fi] * cg[1].z + cbv[1].z,
      (cA[fi][1].w - mu[fi]) * iv[fi] * cg[1].w + cbv[1].w };
    split8(v, ah[fi], al[fi]);
  }
#pragma unroll
  for (int z = 0; z < 3; z++) {
    f32x4 (*ac)[2] = (z == 0) ? aq : ((z == 1) ? ak : av);
#pragma unroll
    for (int fj = 0; fj < 2; fj++) {
      const int n = wn + fj * 16 + r16;
      const int off = boff32(n, q);
      short8 bh = *(const short8*)&cbuf[(z * 2) * 2048 + off];
      short8 bl = *(const short8*)&cbuf[(z * 2 + 1) * 2048 + off];
#pragma unroll
      for (int fi = 0; fi < 4; fi++) {
        ac[fi][fj] = MFMA(ah[fi], bh, ac[fi][fj]);
        ac[fi][fj] = MFMA(ah[fi], bl, ac[fi][fj]);
        ac[fi][fj] = MFMA(al[fi], bh, ac[fi][fj]);
      }
    }
  }
}

// ---------------------------------------------------------------------------
// Phase A: per (batch,head). LN1(atomic stats) fused into QKV A-frags; dbuf-2
// weight DMA with vmcnt/s_barrier pipeline; Q,K->LDS; V->vT; MFMA attention.
// ---------------------------------------------------------------------------
__device__ void phaseA(const KArgs& a, int l, int head, int grp, const float* ln1,
                       const float* hR, u16* obh_g, u16* obl_g, char* sm, int tid)
{
  const int wave = tid >> 6, lane = tid & 63;
  const int q = lane >> 4, r16 = lane & 15;
  const int wm = (wave >> 1) * 32, wn = (wave & 1) * 32;
  const size_t wOff = (size_t)l * 512 * 512;
  const size_t hOff = (size_t)head * 64 * 512;

  const float* lg = a.ln1g + l * 512;
  const float* lb = a.ln1b + l * 512;
  const u16* const wz[6] = { a.WTh[0] + wOff + hOff, a.WTl[0] + wOff + hOff,
                             a.WTh[1] + wOff + hOff, a.WTl[1] + wOff + hOff,
                             a.WTh[2] + wOff + hOff, a.WTl[2] + wOff + hOff };
  u16* vT = a.vT + (size_t)(grp * 8 + head) * 64 * 128;
  u16* const buf[2] = { (u16*)sm, (u16*)sm + 12288 };   // 24576 B each

  int RB[4];
#pragma unroll
  for (int fi = 0; fi < 4; fi++) RB[fi] = (fi >> 1) * 64 + wm + (fi & 1) * 16;

  // LN1 stats (atomics from prev iteration) -> sc loads + explicit drain
  f32x2 st4[4];
#pragma unroll
  for (int fi = 0; fi < 4; fi++) st4[fi] = ldg_cs2(ln1 + (RB[fi] + r16) * 2);
  vmwait0();
  float mu[4], iv[4];
#pragma unroll
  for (int fi = 0; fi < 4; fi++) {
    const float m = st4[fi].x * (1.0f / 512.0f);
    mu[fi] = m;
    iv[fi] = rsqrtf(st4[fi].y * (1.0f / 512.0f) - m * m + 1e-5f);
  }

  f32x4 aq[4][2] = {}, ak[4][2] = {}, av[4][2] = {};
  f32x4 Ae[4][2], Ao[4][2], ge[2], go[2], be_[2], bo_[2];

  // A(0) -> even set: 8 sc + 4 cached = 12 vm-insts (VM12 invariant at ks=0)
#pragma unroll
  for (int fi = 0; fi < 4; fi++) {
    const float* hp = hR + (size_t)(RB[fi] + r16) * DM + q * 8;
    Ae[fi][0] = ldg_cs4(hp); Ae[fi][1] = ldg_cs4(hp + 4);
  }
  ge[0] = ldg_nrm4(lg + q * 8); ge[1] = ldg_nrm4(lg + q * 8 + 4);
  be_[0] = ldg_nrm4(lb + q * 8); be_[1] = ldg_nrm4(lb + q * 8 + 4);
  // stage 0 was prefetched inside the preceding barrier (pfA)

#pragma unroll
  for (int kp = 0; kp < 8; kp++) {
    stepA(2 * kp,     hR, lg, lb, wz, buf, tid, q, r16, wn, RB, mu, iv,
          Ae, ge, be_, Ao, go, bo_, aq, ak, av);
    stepA(2 * kp + 1, hR, lg, lb, wz, buf, tid, q, r16, wn, RB, mu, iv,
          Ao, go, bo_, Ae, ge, be_, aq, ak, av);
  }
  __syncthreads();   // arena free for Q/K overlay

  u16 (*Qb)[66] = (u16(*)[66])sm;
  u16 (*Kb)[66] = (u16(*)[66])(sm + 16896);
  {
    const float* bq = a.bias6[0] + l * 512 + head * 64;
    const float* bk = a.bias6[1] + l * 512 + head * 64;
    const float* bv = a.bias6[2] + l * 512 + head * 64;
#pragma unroll
    for (int fi = 0; fi < 4; fi++) {
#pragma unroll
      for (int fj = 0; fj < 2; fj++) {
        const int col = wn + fj * 16 + r16;
        const int row0 = RB[fi] + q * 4;
        const float bqv = bq[col], bkv = bk[col], bvv = bv[col];
#pragma unroll
        for (int i = 0; i < 4; i++) {
          Qb[row0 + i][col] = f2bf(aq[fi][fj][i] + bqv);
          Kb[row0 + i][col] = f2bf(ak[fi][fj][i] + bkv);
          vT[(size_t)col * 128 + row0 + i] = f2bf(av[fi][fj][i] + bvv);  // block-local
        }
      }
    }
  }
  __syncthreads();

  const int m0 = wave * 32;
  f32x4 sc[2][8] = {};
#pragma unroll
  for (int kk = 0; kk < 2; kk++) {
    short8 aQ[2];
#pragma unroll
    for (int fi = 0; fi < 2; fi++)
      aQ[fi] = *(const short8*)&Qb[m0 + fi * 16 + r16][kk * 32 + q * 8];
#pragma unroll
    for (int nt = 0; nt < 8; nt++) {
      short8 bK = *(const short8*)&Kb[nt * 16 + r16][kk * 32 + q * 8];
#pragma unroll
      for (int fi = 0; fi < 2; fi++) sc[fi][nt] = MFMA(aQ[fi], bK, sc[fi][nt]);
    }
  }
  __syncthreads();

#pragma unroll
  for (int fi = 0; fi < 2; fi++) {
#pragma unroll
    for (int i = 0; i < 4; i++) {
      float mrow = -1e30f;
#pragma unroll
      for (int nt = 0; nt < 8; nt++) {
        float v = sc[fi][nt][i] * 0.125f; sc[fi][nt][i] = v; mrow = fmaxf(mrow, v);
      }
#pragma unroll
      for (int o = 1; o < 16; o <<= 1) mrow = fmaxf(mrow, __shfl_xor(mrow, o, 64));
      float lsum = 0.f;
#pragma unroll
      for (int nt = 0; nt < 8; nt++) {
        float p = __expf(sc[fi][nt][i] - mrow); sc[fi][nt][i] = p; lsum += p;
      }
#pragma unroll
      for (int o = 1; o < 16; o <<= 1) lsum += __shfl_xor(lsum, o, 64);
      const float inv = 1.0f / lsum;
#pragma unroll
      for (int nt = 0; nt < 8; nt++) sc[fi][nt][i] *= inv;
    }
  }
  u16 (*Pb)[132] = (u16(*)[132])sm;
#pragma unroll
  for (int fi = 0; fi < 2; fi++)
#pragma unroll
    for (int nt = 0; nt < 8; nt++)
#pragma unroll
      for (int i = 0; i < 4; i++)
        Pb[m0 + fi * 16 + q * 4 + i][nt * 16 + r16] = f2bf(sc[fi][nt][i]);
  __syncthreads();

  f32x4 oa[2][4] = {};
#pragma unroll
  for (int kt = 0; kt < 4; kt++) {
    short8 aP[2];
#pragma unroll
    for (int fi = 0; fi < 2; fi++)
      aP[fi] = *(const short8*)&Pb[m0 + fi * 16 + r16][kt * 32 + q * 8];
#pragma unroll
    for (int nt = 0; nt < 4; nt++) {
      short8 bV = *(const short8*)(vT + (size_t)(nt * 16 + r16) * 128 + kt * 32 + q * 8);
#pragma unroll
      for (int fi = 0; fi < 2; fi++) oa[fi][nt] = MFMA(aP[fi], bV, oa[fi][nt]);
    }
  }
#pragma unroll
  for (int fi = 0; fi < 2; fi++)
#pragma unroll
    for (int nt = 0; nt < 4; nt++)
#pragma unroll
      for (int i = 0; i < 4; i++) {
        const int row = m0 + fi * 16 + q * 4 + i;
        const int col = head * 64 + nt * 16 + r16;
        float v = oa[fi][nt][i];
        u16 hv = f2bf(v);
        stg_cs_u16(&obh_g[(size_t)row * DM + col], hv);
        stg_cs_u16(&obl_g[(size_t)row * DM + col], f2bf(v - bf2f(hv)));
      }
}

// ---------------------------------------------------------------------------
// tileBD pipeline step (full unroll; KT compile-time).
// ---------------------------------------------------------------------------
template<int KT>
__device__ __forceinline__ void stepBD(
    int ks, const u16* Ahi, const u16* Alo, const u16* bh0, const u16* bl0,
    char* sm, int tid, int q, int r16, int bm, int wm, int wn,
    short8 (&ch)[2][2], short8 (&cl)[2][2],
    short8 (&nh)[2][2], short8 (&nl)[2][2], f32x4 (&acc)[2][2])
{
  constexpr int K = KT, nk = KT >> 6;
  if (ks + 1 < nk) {                  // A(ks+1): 8 vm-insts into nxt set
#pragma unroll
    for (int kk = 0; kk < 2; kk++)
#pragma unroll
      for (int fi = 0; fi < 2; fi++) {
        const size_t ao = (size_t)(bm + wm + fi * 16 + r16) * K + (ks + 1) * 64 + kk * 32 + q * 8;
        nh[kk][fi] = ldg_cs_s8(Ahi + ao);
        nl[kk][fi] = ldg_cs_s8(Alo + ao);
      }
    if (ks == 0) WAITB(VM8);          // retires bias[2]+A(0)[8]
    else         WAITB(VM12);         // retires DMA(ks)[4]+A(ks)[8]
  } else {
    WAITB(VM0);
  }
  BARB();
  if (ks + 2 < nk) {                  // DMA(ks+2) -> slot (ks+2)%3
    u16* slot = (u16*)(sm + ((ks + 2) % 3) * 16384);
    dmaW64(bh0, K, (ks + 2) * 64, slot, tid);
    dmaW64(bl0, K, (ks + 2) * 64, slot + 4096, tid);
  }
  const u16* Bsh = (const u16*)(sm + (ks % 3) * 16384);
  const u16* Bsl = Bsh + 4096;
#pragma unroll
  for (int kk = 0; kk < 2; kk++) {
#pragma unroll
    for (int fj = 0; fj < 2; fj++) {
      const int n = wn + fj * 16 + r16;
      const int off = boff64(n, kk * 4 + q);
      short8 bh = *(const short8*)&Bsh[off];
      short8 bl = *(const short8*)&Bsl[off];
#pragma unroll
      for (int fi = 0; fi < 2; fi++) {
        acc[fi][fj] = MFMA(ch[kk][fi], bh, acc[fi][fj]);
        acc[fi][fj] = MFMA(ch[kk][fi], bl, acc[fi][fj]);
        acc[fi][fj] = MFMA(cl[kk][fi], bh, acc[fi][fj]);
      }
    }
  }
}

// ---------------------------------------------------------------------------
// tileBD: 64x64 split-bf16x3 GEMM, A pre-split from global, 3-deep ring DMA
// with vmcnt/s_barrier pipeline. Stages 0,1 prefetched in preceding barrier.
// ---------------------------------------------------------------------------
template<int EP, int KT>
__device__ void tileBD(const u16* Ahi, const u16* Alo,
                       const u16* Whi, const u16* Wlo, const float* bias,
                       int bm, int bn, float* hIO, const float* Xx,
                       float* lnacc, char* sm, int tid)
{
  constexpr int K = KT;
  const int wave = tid >> 6, lane = tid & 63;
  const int q = lane >> 4, r16 = lane & 15;
  const int wm = (wave >> 1) * 32, wn = (wave & 1) * 32;
  const u16* bh0 = Whi + (size_t)bn * K;
  const u16* bl0 = Wlo + (size_t)bn * K;
  f32x4 acc[2][2] = {};

  // bias preload: oldest vm-ops, retired by the ks=0 VM8 wait
  float bv2[2];
  bv2[0] = ldg_nrm1(bias + bn + wn + r16);
  bv2[1] = ldg_nrm1(bias + bn + wn + 16 + r16);

  short8 Eh[2][2], El[2][2], Oh[2][2], Ol[2][2];
#pragma unroll
  for (int kk = 0; kk < 2; kk++)
#pragma unroll
    for (int fi = 0; fi < 2; fi++) {
      const size_t ao = (size_t)(bm + wm + fi * 16 + r16) * K + kk * 32 + q * 8;
      Eh[kk][fi] = ldg_cs_s8(Ahi + ao);
      El[kk][fi] = ldg_cs_s8(Alo + ao);
    }

#pragma unroll
  for (int kp = 0; kp < (KT >> 7); kp++) {
    stepBD<KT>(2 * kp,     Ahi, Alo, bh0, bl0, sm, tid, q, r16, bm, wm, wn,
               Eh, El, Oh, Ol, acc);
    stepBD<KT>(2 * kp + 1, Ahi, Alo, bh0, bl0, sm, tid, q, r16, bm, wm, wn,
               Oh, Ol, Eh, El, acc);
  }

  float outv[2][2][4];
#pragma unroll
  for (int fi = 0; fi < 2; fi++) {
    float hld[2][4], xld[2][4];
#pragma unroll
    for (int fj = 0; fj < 2; fj++) {
      const int col = bn + wn + fj * 16 + r16;
      const int row0 = bm + wm + fi * 16 + q * 4;
#pragma unroll
      for (int i = 0; i < 4; i++) {
        const size_t off = (size_t)(row0 + i) * DM + col;
        hld[fj][i] = ldg_cs1(hIO + off);
        if (EP == EP_TANHLERP) xld[fj][i] = ldg_nrm1(Xx + off);
      }
    }
    vmwait0();
#pragma unroll
    for (int fj = 0; fj < 2; fj++) {
      const int col = bn + wn + fj * 16 + r16;
      const float bvv = bv2[fj];
      const int row0 = bm + wm + fi * 16 + q * 4;
#pragma unroll
      for (int i = 0; i < 4; i++) {
        const size_t off = (size_t)(row0 + i) * DM + col;
        float hv;
        if (EP == EP_RESID) {
          hv = hld[fj][i] + acc[fi][fj][i] + bvv;
        } else {
          hv = 0.5f * hld[fj][i] + 0.5f * tanhf(hld[fj][i] + acc[fi][fj][i] + bvv + xld[fj][i]);
        }
        stg_cs1(hIO + off, hv);
        outv[fi][fj][i] = hv;
      }
      (void)col;
    }
  }
#pragma unroll
  for (int fi = 0; fi < 2; fi++)
#pragma unroll
    for (int i = 0; i < 4; i++) {
      float a0 = outv[fi][0][i], a1 = outv[fi][1][i];
      float s1 = a0 + a1, s2 = a0 * a0 + a1 * a1;
#pragma unroll
      for (int o = 1; o < 16; o <<= 1) { s1 += __shfl_xor(s1, o, 64); s2 += __shfl_xor(s2, o, 64); }
      if (r16 == 0) {
        const int row = bm + wm + fi * 16 + q * 4 + i;
        atomAddF(&lnacc[row * 2], s1);
        atomAddF(&lnacc[row * 2 + 1], s2);
      }
    }
}

// ---------------------------------------------------------------------------
// tileC2 pipeline step (full unroll; s compile-time).
// ---------------------------------------------------------------------------
__device__ __forceinline__ void stepC2(
    int s, const float* h_g, const float* lg, const float* lb,
    const u16* const (&whB)[2], const u16* const (&wlB)[2],
    const float (&b1v)[2][2], u16* ffh_g, u16* ffl_g, int bn0, int bm,
    char* sm, int tid, int q, int r16, int wm, int wn,
    const float (&mu)[2], const float (&iv)[2],
    f32x4 (&cA)[2][2][2], f32x4 (&cg)[2][2], f32x4 (&cbv)[2][2],
    f32x4 (&nA)[2][2][2], f32x4 (&ng)[2][2], f32x4 (&nbv)[2][2],
    f32x4 (&acc)[2][2])
{
  if (s + 1 < 16) {                   // A(s+1): 16 vm-insts into nxt set
    const int kb1 = ((s + 1) & 7) * 64;
#pragma unroll
    for (int kk = 0; kk < 2; kk++) {
      const int kb = kb1 + kk * 32 + q * 8;
#pragma unroll
      for (int fi = 0; fi < 2; fi++) {
        const float* hp = h_g + (size_t)(bm + wm + fi * 16 + r16) * DM + kb;
        nA[kk][fi][0] = ldg_cs4(hp); nA[kk][fi][1] = ldg_cs4(hp + 4);
      }
      ng[kk][0] = ldg_nrm4(lg + kb); ng[kk][1] = ldg_nrm4(lg + kb + 4);
      nbv[kk][0] = ldg_nrm4(lb + kb); nbv[kk][1] = ldg_nrm4(lb + kb + 4);
    }
    if (s == 0) WAITB(VM16);          // retires A(0)[16]
    else        WAITB(VM20);          // retires DMA(s)[4]+A(s)[16]
  } else {
    WAITB(VM0);
  }
  BARB();
  if (s + 2 < 16) {
    const int t2 = (s + 2) >> 3, k2 = ((s + 2) & 7) * 64;
    u16* slot = (u16*)(sm + ((s + 2) % 3) * 16384);
    dmaW64(whB[t2], 512, k2, slot, tid);
    dmaW64(wlB[t2], 512, k2, slot + 4096, tid);
  }
  const u16* Bsh = (const u16*)(sm + (s % 3) * 16384);
  const u16* Bsl = Bsh + 4096;
#pragma unroll
  for (int kk = 0; kk < 2; kk++) {
    short8 ah[2], al[2];
#pragma unroll
    for (int fi = 0; fi < 2; fi++) {
      float v[8] = {
        (cA[kk][fi][0].x - mu[fi]) * iv[fi] * cg[kk][0].x + cbv[kk][0].x,
        (cA[kk][fi][0].y - mu[fi]) * iv[fi] * cg[kk][0].y + cbv[kk][0].y,
        (cA[kk][fi][0].z - mu[fi]) * iv[fi] * cg[kk][0].z + cbv[kk][0].z,
        (cA[kk][fi][0].w - mu[fi]) * iv[fi] * cg[kk][0].w + cbv[kk][0].w,
        (cA[kk][fi][1].x - mu[fi]) * iv[fi] * cg[kk][1].x + cbv[kk][1].x,
        (cA[kk][fi][1].y - mu[fi]) * iv[fi] * cg[kk][1].y + cbv[kk][1].y,
        (cA[kk][fi][1].z - mu[fi]) * iv[fi] * cg[kk][1].z + cbv[kk][1].z,
        (cA[kk][fi][1].w - mu[fi]) * iv[fi] * cg[kk][1].w + cbv[kk][1].w };
      split8(v, ah[fi], al[fi]);
    }
#pragma unroll
    for (int fj = 0; fj < 2; fj++) {
      const int n = wn + fj * 16 + r16;
      const int off = boff64(n, kk * 4 + q);
      short8 bh = *(const short8*)&Bsh[off];
      short8 bl = *(const short8*)&Bsl[off];
#pragma unroll
      for (int fi = 0; fi < 2; fi++) {
        acc[fi][fj] = MFMA(ah[fi], bh, acc[fi][fj]);
        acc[fi][fj] = MFMA(ah[fi], bl, acc[fi][fj]);
        acc[fi][fj] = MFMA(al[fi], bh, acc[fi][fj]);
      }
    }
  }
  if ((s & 7) == 7) {                 // tile (s>>3) epilogue
    const int t = s >> 3;
#pragma unroll
    for (int fi = 0; fi < 2; fi++)
#pragma unroll
      for (int fj = 0; fj < 2; fj++) {
        const int col = bn0 + t * 512 + wn + fj * 16 + r16;
        const float bvv = b1v[t][fj];
        const int row0 = bm + wm + fi * 16 + q * 4;
#pragma unroll
        for (int i = 0; i < 4; i++) {
          const size_t off = (size_t)(row0 + i) * 1024 + col;
          float r = fmaxf(acc[fi][fj][i] + bvv, 0.f);
          u16 hv = f2bf(r);
          stg_cs_u16(ffh_g + off, hv);
          stg_cs_u16(ffl_g + off, f2bf(r - bf2f(hv)));
        }
        acc[fi][fj] = (f32x4){0.f, 0.f, 0.f, 0.f};
      }
  }
}

// ---------------------------------------------------------------------------
// tileC2: LN2(atomic stats) + FFN1 + ReLU, two chained 64x64 tiles as one
// 16-stage ring-pipelined loop (weight base switches at stage 8).
// ---------------------------------------------------------------------------
__device__ void tileC2(const KArgs& a, int l, const float* h_g, const float* lnsrc,
                       u16* ffh_g, u16* ffl_g, int bm, int bn0, char* sm, int tid)
{
  const int wave = tid >> 6, lane = tid & 63;
  const int q = lane >> 4, r16 = lane & 15;
  const int wm = (wave >> 1) * 32, wn = (wave & 1) * 32;
  const size_t fOff = (size_t)l * 512 * 1024;
  const float* lg = a.ln2g + l * 512;
  const float* lb = a.ln2b + l * 512;
  const float* b1 = a.bias6[4] + l * 1024;

  // LN2 stats + b1 bias preload, then explicit drain (vmcnt back to 0)
  f32x2 stl[2];
#pragma unroll
  for (int fi = 0; fi < 2; fi++)
    stl[fi] = ldg_cs2(lnsrc + (bm + wm + fi * 16 + r16) * 2);
  float b1v[2][2];
#pragma unroll
  for (int t = 0; t < 2; t++)
#pragma unroll
    for (int fj = 0; fj < 2; fj++)
      b1v[t][fj] = ldg_nrm1(b1 + bn0 + t * 512 + wn + fj * 16 + r16);
  vmwait0();

  float mu[2], iv[2];
#pragma unroll
  for (int fi = 0; fi < 2; fi++) {
    const float m = stl[fi].x * (1.0f / 512.0f);
    mu[fi] = m;
    iv[fi] = rsqrtf(stl[fi].y * (1.0f / 512.0f) - m * m + 1e-5f);
  }

  const u16* const whB[2] = { a.WTh[4] + fOff + (size_t)bn0 * 512,
                              a.WTh[4] + fOff + (size_t)(bn0 + 512) * 512 };
  const u16* const wlB[2] = { a.WTl[4] + fOff + (size_t)bn0 * 512,
                              a.WTl[4] + fOff + (size_t)(bn0 + 512) * 512 };
  f32x4 acc[2][2] = {};

  f32x4 Ae[2][2][2], Ao[2][2][2], ge[2][2], go[2][2], be_[2][2], bo_[2][2];
  // A(0) -> even set: 16 vm-insts (VM16 invariant at s=0)
#pragma unroll
  for (int kk = 0; kk < 2; kk++) {
    const int kb = kk * 32 + q * 8;
#pragma unroll
    for (int fi = 0; fi < 2; fi++) {
      const float* hp = h_g + (size_t)(bm + wm + fi * 16 + r16) * DM + kb;
      Ae[kk][fi][0] = ldg_cs4(hp); Ae[kk][fi][1] = ldg_cs4(hp + 4);
    }
    ge[kk][0] = ldg_nrm4(lg + kb); ge[kk][1] = ldg_nrm4(lg + kb + 4);
    be_[kk][0] = ldg_nrm4(lb + kb); be_[kk][1] = ldg_nrm4(lb + kb + 4);
  }

#pragma unroll
  for (int kp = 0; kp < 8; kp++) {
    stepC2(2 * kp,     h_g, lg, lb, whB, wlB, b1v, ffh_g, ffl_g, bn0, bm, sm, tid,
           q, r16, wm, wn, mu, iv, Ae, ge, be_, Ao, go, bo_, acc);
    stepC2(2 * kp + 1, h_g, lg, lb, whB, wlB, b1v, ffh_g, ffl_g, bn0, bm, sm, tid,
           q, r16, wm, wn, mu, iv, Ao, go, bo_, Ae, ge, be_, acc);
  }
}

// ---------------------------------------------------------------------------
__global__ __launch_bounds__(256, 1) void persist(KArgs a)
{
  __shared__ __align__(16) char smem[SMEM_BYTES];
  const int tid = threadIdx.x;
  const int bid = blockIdx.x;
  const int grp = bid & 7;
  const int gb  = bid >> 3;

  // ---- phase 0: weight split-transpose + embed + zero h + LN sums ----
  {
    float (*tile)[33] = (float (*)[33])smem;
    const int tx = tid & 31, ty = tid >> 5;
    for (int t = bid; t < 4096; t += NB) {
      int tensor, z, k0, n0, K, N;
      if (t < 2048)      { tensor = t >> 9;  int rem = t & 511;  z = rem >> 8; int r2 = rem & 255;
                           K = 512;  N = 512;  k0 = (r2 >> 4) << 5; n0 = (r2 & 15) << 5; }
      else if (t < 3072) { tensor = 4;       int rem = t - 2048; z = rem >> 9; int r2 = rem & 511;
                           K = 512;  N = 1024; k0 = (r2 >> 5) << 5; n0 = (r2 & 31) << 5; }
      else               { tensor = 5;       int rem = t - 3072; z = rem >> 9; int r2 = rem & 511;
                           K = 1024; N = 512;  k0 = (r2 >> 4) << 5; n0 = (r2 & 15) << 5; }
      const float* src = a.W[tensor]   + (size_t)z * K * N;
      u16* dhi         = a.WTh[tensor] + (size_t)z * K * N;
      u16* dlo         = a.WTl[tensor] + (size_t)z * K * N;
      __syncthreads();
#pragma unroll
      for (int r = 0; r < 4; r++) {
        int k = ty + r * 8;
        tile[k][tx] = src[(size_t)(k0 + k) * N + n0 + tx];
      }
      __syncthreads();
#pragma unroll
      for (int r = 0; r < 4; r++) {
        int n = ty + r * 8;
        float w = tile[tx][n];
        u16 hi = f2bf(w);
        dhi[(size_t)(n0 + n) * K + k0 + tx] = hi;
        dlo[(size_t)(n0 + n) * K + k0 + tx] = f2bf(w - bf2f(hi));
      }
    }
    for (int idx = bid * 256 + tid; idx < NTOK * DM; idx += NB * 256) {
      int t = idx >> 9, d = idx & 511, ss = t & 127;
      a.xe[idx] = a.tok[(size_t)a.x[t] * DM + d] + a.pos[ss * DM + d];
      a.h[idx] = 0.0f;
    }
    const int nstat = (41 + 40) * 8 * 256;
    for (int idx = bid * 256 + tid; idx < nstat; idx += NB * 256)
      a.ln1sum[idx] = 0.0f;
  }
  // one-time STRONG barrier: weights become clean, cacheable, never
  // invalidated again.
  bar_arrive(a.bar + 256, tid);
  if (gb < 8) pfA(a, 0, gb, smem, tid);
  bar_wait(a.bar + 256, NB, tid);

  unsigned* gctr = a.bar + grp * 32;
  unsigned tgt = 0;
  const size_t r512  = (size_t)grp * 128 * 512;
  const size_t r1024 = (size_t)grp * 128 * 1024;
  float* h_g  = a.h  + r512;
  float* xe_g = a.xe + r512;
  u16 *obh_g = a.obh + r512, *obl_g = a.obl + r512;
  u16 *ffh_g = a.ffh + r1024, *ffl_g = a.ffl + r1024;
  const int bn = (gb & 7) * 64, bm = (gb >> 3) * 64;

  for (int it = 0; it < 40; it++) {
    const int l = it & 1;
    const size_t wOff = (size_t)l * 512 * 512;
    const size_t fOff = (size_t)l * 512 * 1024;
    float* ln1it = a.ln1sum + ((size_t)it * 8 + grp) * 256;
    float* ln2it = a.ln2sum + ((size_t)it * 8 + grp) * 256;
    float* ln1nx = a.ln1sum + ((size_t)(it + 1) * 8 + grp) * 256;

    if (gb < 8) phaseA(a, l, gb, grp, ln1it, h_g, obh_g, obl_g, smem, tid);
    bar_arrive_weak(gctr, tid); tgt += 16;
    pfBD2(a.WTh[3] + wOff + (size_t)bn * 512, a.WTl[3] + wOff + (size_t)bn * 512, 512, smem, tid);
    bar_wait_weak(gctr, tgt, tid);

    tileBD<EP_RESID, 512>(obh_g, obl_g, a.WTh[3] + wOff, a.WTl[3] + wOff,
                          a.bias6[3] + l * 512, bm, bn, h_g, nullptr, ln2it, smem, tid);
    bar_arrive_weak(gctr, tid); tgt += 16;
    pfBD2(a.WTh[4] + fOff + (size_t)bn * 512, a.WTl[4] + fOff + (size_t)bn * 512, 512, smem, tid);
    bar_wait_weak(gctr, tgt, tid);

    tileC2(a, l, h_g, ln2it, ffh_g, ffl_g, bm, bn, smem, tid);
    bar_arrive_weak(gctr, tid); tgt += 16;
    pfBD2(a.WTh[5] + fOff + (size_t)bn * 1024, a.WTl[5] + fOff + (size_t)bn * 1024, 1024, smem, tid);
    bar_wait_weak(gctr, tgt, tid);

    tileBD<EP_TANHLERP, 1024>(ffh_g, ffl_g, a.WTh[5] + fOff, a.WTl[5] + fOff,
                              a.bias6[5] + l * 512, bm, bn, h_g, xe_g, ln1nx, smem, tid);
    bar_arrive_weak(gctr, tid); tgt += 16;
    if (it + 1 < 40 && gb < 8) pfA(a, (it + 1) & 1, gb, smem, tid);
    bar_wait_weak(gctr, tgt, tid);
  }

  // group-local mean: hm[grp][512]
  {
    const int dim = gb * 32 + (tid >> 3);
    const int sub = tid & 7;
    float tl[16];
#pragma unroll
    for (int k2 = 0; k2 < 16; k2++)
      tl[k2] = ldg_cs1(h_g + (size_t)(sub + k2 * 8) * DM + dim);
    vmwait0();
    float sv = 0.f;
#pragma unroll
    for (int k2 = 0; k2 < 16; k2++) sv += tl[k2];
    sv += __shfl_xor(sv, 1, 64); sv += __shfl_xor(sv, 2, 64); sv += __shfl_xor(sv, 4, 64);
    if (sub == 0) stg_cs1(&a.hm[grp * 512 + dim], sv * (1.0f / 128.0f));
  }
  bar_arrive_weak(gctr, tid); tgt += 16;
  bar_wait_weak(gctr, tgt, tid);

  // group-local head: out[grp][1000]. hm lines were never cached anywhere
  // before the sc-stores above (region untouched pre-barrier), so normal
  // cached loads observe the LLC copy.
  {
    const int idx = tid >> 2;
    const int n = gb * 63 + idx;
    const int sub = tid & 3;
    if (idx < 63 && n < 1000) {
      const float* hr = a.hm + grp * 512 + sub * 128;
      const float* wr = a.hw + (size_t)(sub * 128) * 1000 + n;
      float sv = 0.f;
      for (int j = 0; j < 128; j++) sv = fmaf(hr[j], wr[(size_t)j * 1000], sv);
      sv += __shfl_xor(sv, 1, 64);
      sv += __shfl_xor(sv, 2, 64);
      if (sub == 0) a.out[grp * 1000 + n] = sv + a.hb[n];
    }
  }
}

// ---------------------------------------------------------------------------
extern "C" void kernel_launch(void* const* d_in, const int* in_sizes, int n_in,
                              void* d_out, int out_size, void* d_ws, size_t ws_size,
                              hipStream_t stream)
{
  (void)in_sizes; (void)n_in; (void)out_size; (void)ws_size;
  KArgs a;
  a.x    = (const int*)d_in[0];
  a.tok  = (const float*)d_in[2];
  a.pos  = (const float*)d_in[3];
  a.W[0] = (const float*)d_in[4];   a.bias6[0] = (const float*)d_in[5];
  a.W[1] = (const float*)d_in[6];   a.bias6[1] = (const float*)d_in[7];
  a.W[2] = (const float*)d_in[8];   a.bias6[2] = (const float*)d_in[9];
  a.W[3] = (const float*)d_in[10];  a.bias6[3] = (const float*)d_in[11];
  a.W[4] = (const float*)d_in[12];  a.bias6[4] = (const float*)d_in[13];
  a.W[5] = (const float*)d_in[14];  a.bias6[5] = (const float*)d_in[15];
  a.ln1g = (const float*)d_in[16];
  a.ln1b = (const float*)d_in[17];
  a.ln2g = (const float*)d_in[18];
  a.ln2b = (const float*)d_in[19];
  a.hw   = (const float*)d_in[20];
  a.hb   = (const float*)d_in[21];
  a.out  = (float*)d_out;

  char* ws = (char*)d_ws;
  const size_t MB = 1ull << 20;
  a.xe   = (float*)(ws + 0 * MB);
  a.h    = (float*)(ws + 2 * MB);
  a.obh  = (u16*)(ws + 4 * MB);
  a.obl  = (u16*)(ws + 5 * MB);
  a.ffh  = (u16*)(ws + 6 * MB);
  a.ffl  = (u16*)(ws + 8 * MB);
  a.hm   = (float*)(ws + 10 * MB);
  a.vT   = (u16*)(ws + 11 * MB);
  a.WTh[0] = (u16*)(ws + 12 * MB);  a.WTl[0] = (u16*)(ws + 13 * MB);
  a.WTh[1] = (u16*)(ws + 14 * MB);  a.WTl[1] = (u16*)(ws + 15 * MB);
  a.WTh[2] = (u16*)(ws + 16 * MB);  a.WTl[2] = (u16*)(ws + 17 * MB);
  a.WTh[3] = (u16*)(ws + 18 * MB);  a.WTl[3] = (u16*)(ws + 19 * MB);
  a.WTh[4] = (u16*)(ws + 20 * MB);  a.WTl[4] = (u16*)(ws + 22 * MB);
  a.WTh[5] = (u16*)(ws + 24 * MB);  a.WTl[5] = (u16*)(ws + 26 * MB);
  a.bar    = (unsigned*)(ws + 28 * MB);
  a.ln1sum = (float*)(ws + 29 * MB);
  a.ln2sum = a.ln1sum + (size_t)41 * 8 * 256;

  bar_init<<<1, 256, 0, stream>>>(a.bar);
  persist<<<NB, 256, 0, stream>>>(a);
}

// Round 3
// 5252.571 us; speedup vs baseline: 1.9274x; 1.9274x over previous
//
#include <hip/hip_runtime.h>
#include <hip/hip_bf16.h>
#include <math.h>

// B=8, S=128; D=512; H=8, HD=64; L=2; steps=20 (fixed).
// 8 groups (=batches) x 16 blocks. 4 phases/iter. K-loops pipelined with
// s_waitcnt vmcnt(N) + raw s_barrier (DMA stays in flight across barriers);
// B/C/D use a 3-deep LDS ring; stages prefetched around the group barriers.
//
// R3: runtime-verified XCD-local groups.
//  - R0 evidence: 44MB/iter FETCH = weight refetch after each acquire L2-inv
//    (the fences' cost is weight EVICTION, not the tag walk).
//  - R2 evidence: sc0sc1 loads bypass L2 -> +2.7GB fetch, 1.7x slower; but it
//    PASSED -> sc-store/weak-barrier visibility at LLC is correct.
//  - Therefore: detect block->XCD placement at runtime (HW_REG_XCC_ID). If
//    every XCD hosts exactly 16 blocks, remap grp=xcd, gb=rank-in-xcd: each
//    group's 16 blocks share ONE L2 -> normal cached loads/stores are
//    coherent for all inter-phase tensors. Group barrier then needs NO L2
//    cache ops: arrive = vmcnt(0)+syncthreads+relaxed atomic; wait = poll +
//    buffer_inv sc0 (L1-only, per-CU, cheap) + vmcnt(0). Weights stay L2-
//    resident forever.  If placement is unbalanced: exact R0 release/acquire
//    fallback (correct under any mapping).
//  - ln-stats are atomic-written (atomics bypass L2 to LLC), so their reads
//    use sc0sc1 loads in BOTH paths (avoids a stale-clean-L2-line hazard).
#define NTOK 1024
#define DM   512
#define NB   128

typedef unsigned short u16;
typedef __attribute__((ext_vector_type(8))) short short8;
typedef __attribute__((ext_vector_type(4))) float f32x4;
typedef __attribute__((ext_vector_type(2))) float f32x2;
typedef __attribute__((address_space(1))) const void* as1cv;
typedef __attribute__((address_space(3))) void* as3v;

// s_waitcnt imms (gfx9): vmcnt[3:0]|[15:14], expcnt=7<<4, lgkm=15<<8
#define VM12 0x0F7C
#define VM20 0x4F74
#define VM0  0x0F70

__device__ inline u16 f2bf(float f) {
  __hip_bfloat16 h = __float2bfloat16(f);
  return *reinterpret_cast<u16*>(&h);
}
__device__ inline float bf2f(u16 b) {
  union { unsigned u; float f; } x; x.u = (unsigned)b << 16; return x.f;
}
__device__ inline void split8(const float* v, short8& hi, short8& lo) {
#pragma unroll
  for (int j = 0; j < 8; j++) {
    u16 h = f2bf(v[j]);
    hi[j] = (short)h;
    lo[j] = (short)f2bf(v[j] - bf2f(h));
  }
}
__device__ __forceinline__ f32x4 MFMA(short8 a, short8 b, f32x4 c) {
  return __builtin_amdgcn_mfma_f32_16x16x32_bf16(a, b, c, 0, 0, 0);
}
__device__ __forceinline__ void atomAddF(float* p, float v) {
  __hip_atomic_fetch_add(p, v, __ATOMIC_RELAXED, __HIP_MEMORY_SCOPE_AGENT);
}

// sc0 sc1 read-through load (coherence point) for atomic-written ln stats.
__device__ __forceinline__ f32x2 ldg_cs2(const float* p) {
  f32x2 r;
  asm volatile("global_load_dwordx2 %0, %1, off sc0 sc1" : "=v"(r) : "v"(p) : "memory");
  return r;
}
__device__ __forceinline__ void vmwait0() {
  asm volatile("s_waitcnt vmcnt(0)" ::: "memory");
  __builtin_amdgcn_sched_barrier(0);
}

enum { EP_RESID = 1, EP_TANHLERP = 3 };

struct KArgs {
  const int* x;
  const float* tok; const float* pos;
  const float* W[6];
  const float* bias6[6];
  const float* ln1g; const float* ln1b; const float* ln2g; const float* ln2b;
  const float* hw; const float* hb;
  float* out;
  float* xe; float* h;
  u16* obh; u16* obl;
  u16* ffh; u16* ffl;
  u16* vT;
  float* hm;
  u16* WTh[6]; u16* WTl[6];
  float* ln1sum; float* ln2sum;
  unsigned* bar;
};

#define SMEM_BYTES 49152

// ---- strong barrier: full release/acquire (init + unbalanced fallback) ----
__device__ __forceinline__ void bar_arrive(unsigned* ctr, int tid) {
  __syncthreads();     // all waves' stores drained before release
  if (tid == 0)
    __hip_atomic_fetch_add(ctr, 1u, __ATOMIC_RELEASE, __HIP_MEMORY_SCOPE_AGENT);
}
__device__ __forceinline__ void bar_wait(unsigned* ctr, unsigned target, int tid) {
  if (tid == 0) {
    while (__hip_atomic_load(ctr, __ATOMIC_RELAXED, __HIP_MEMORY_SCOPE_AGENT) < target)
      __builtin_amdgcn_s_sleep(2);
    __builtin_amdgcn_fence(__ATOMIC_ACQUIRE, "agent");
  }
  __syncthreads();
}
// ---- fast barrier: XCD-local group, no L2 cache maintenance ---------------
__device__ __forceinline__ void bar_arrive_fast(unsigned* ctr, int tid) {
  asm volatile("s_waitcnt vmcnt(0) lgkmcnt(0)" ::: "memory"); // stores in L2
  __syncthreads();
  if (tid == 0)
    __hip_atomic_fetch_add(ctr, 1u, __ATOMIC_RELAXED, __HIP_MEMORY_SCOPE_AGENT);
}
__device__ __forceinline__ void bar_wait_fast(unsigned* ctr, unsigned target, int tid) {
  if (tid == 0) {
    while (__hip_atomic_load(ctr, __ATOMIC_RELAXED, __HIP_MEMORY_SCOPE_AGENT) < target)
      __builtin_amdgcn_s_sleep(2);
  }
  __syncthreads();
  // L1 is per-CU and not cross-CU coherent: invalidate it (cheap, local).
  asm volatile("buffer_inv sc0" ::: "memory");
  asm volatile("s_waitcnt vmcnt(0)" ::: "memory");
}
__device__ __forceinline__ void g_arrive(bool fast, unsigned* ctr, int tid) {
  if (fast) bar_arrive_fast(ctr, tid); else bar_arrive(ctr, tid);
}
__device__ __forceinline__ void g_wait(bool fast, unsigned* ctr, unsigned t, int tid) {
  if (fast) bar_wait_fast(ctr, t, tid); else bar_wait(ctr, t, tid);
}
__global__ void bar_init(unsigned* bar) { bar[threadIdx.x] = 0u; bar[256 + threadIdx.x] = 0u; }

// ---------------- DMA helpers (XOR swizzle; verified r9) ----------------
__device__ __forceinline__ void dmaW64(const u16* gbase, int K, int k0, u16* lds, int tid) {
  const int wave = tid >> 6, lane = tid & 63;
#pragma unroll
  for (int i = 0; i < 2; i++) {
    const int lc = wave * 128 + i * 64 + lane;
    const int n = lc >> 3, sl = lc & 7;
    const int c = sl ^ (n & 7);
    const u16* g = gbase + (size_t)n * K + k0 + c * 8;
    u16* dst = lds + (size_t)(wave * 128 + i * 64) * 8;
    __builtin_amdgcn_global_load_lds((as1cv)(const void*)g, (as3v)(void*)dst, 16, 0, 0);
  }
}
__device__ __forceinline__ int boff64(int n, int cp) { return n * 64 + ((cp ^ (n & 7)) << 3); }

__device__ __forceinline__ void dmaW32(const u16* gbase, int K, int k0, u16* lds, int tid) {
  const int wave = tid >> 6, lane = tid & 63;
  const int lc = wave * 64 + lane;
  const int p = lc >> 3, s3 = lc & 7;
  const int c3 = s3 ^ (p & 7);
  const int n = p * 2 + (c3 >> 2);
  const int c = c3 & 3;
  const u16* g = gbase + (size_t)n * K + k0 + c * 8;
  u16* dst = lds + (size_t)(wave * 64) * 8;
  __builtin_amdgcn_global_load_lds((as1cv)(const void*)g, (as3v)(void*)dst, 16, 0, 0);
}
__device__ __forceinline__ int boff32(int n, int cq) {
  const int c3 = ((n & 1) << 2) | cq;
  return ((n >> 1) << 6) + ((c3 ^ ((n >> 1) & 7)) << 3);
}

// prefetches (issued between bar_arrive and bar_wait)
__device__ __forceinline__ void pfBD2(const u16* bh0, const u16* bl0, int K, char* sm, int tid) {
  dmaW64(bh0, K, 0,  (u16*)sm, tid);
  dmaW64(bl0, K, 0,  (u16*)sm + 4096, tid);
  dmaW64(bh0, K, 64, (u16*)(sm + 16384), tid);
  dmaW64(bl0, K, 64, (u16*)(sm + 16384) + 4096, tid);
}
__device__ __forceinline__ void pfA(const KArgs& a, int l, int head, char* sm, int tid) {
  const size_t o = (size_t)l * 512 * 512 + (size_t)head * 64 * 512;
  const u16* wz[6] = { a.WTh[0] + o, a.WTl[0] + o, a.WTh[1] + o,
                       a.WTl[1] + o, a.WTh[2] + o, a.WTl[2] + o };
#pragma unroll
  for (int z = 0; z < 6; z++) dmaW32(wz[z], 512, 0, (u16*)sm + z * 2048, tid);
}

// ---------------------------------------------------------------------------
// Phase A: per (batch,head). LN1(atomic stats) fused into QKV A-frags; dbuf-2
// weight DMA with vmcnt/s_barrier pipeline; Q,K->LDS; V->vT; MFMA attention.
// ---------------------------------------------------------------------------
__device__ void phaseA(const KArgs& a, int l, int head, int grp, const float* ln1,
                       const float* hR, u16* obh_g, u16* obl_g, char* sm, int tid)
{
  const int wave = tid >> 6, lane = tid & 63;
  const int q = lane >> 4, r16 = lane & 15;
  const int wm = (wave >> 1) * 32, wn = (wave & 1) * 32;
  const size_t wOff = (size_t)l * 512 * 512;
  const size_t hOff = (size_t)head * 64 * 512;

  const float* lg = a.ln1g + l * 512;
  const float* lb = a.ln1b + l * 512;
  const u16* wz[6] = { a.WTh[0] + wOff + hOff, a.WTl[0] + wOff + hOff,
                       a.WTh[1] + wOff + hOff, a.WTl[1] + wOff + hOff,
                       a.WTh[2] + wOff + hOff, a.WTl[2] + wOff + hOff };
  u16* vT = a.vT + (size_t)(grp * 8 + head) * 64 * 128;
  u16* buf[2] = { (u16*)sm, (u16*)sm + 12288 };   // 24576 B each

  int RB[4];
#pragma unroll
  for (int fi = 0; fi < 4; fi++) RB[fi] = (fi >> 1) * 64 + wm + (fi & 1) * 16;

  // LN1 stats: atomic-written -> sc0sc1 read-through + explicit drain
  f32x2 st4[4];
#pragma unroll
  for (int fi = 0; fi < 4; fi++) st4[fi] = ldg_cs2(ln1 + (RB[fi] + r16) * 2);
  vmwait0();
  float mu[4], iv[4];
#pragma unroll
  for (int fi = 0; fi < 4; fi++) {
    const float m = st4[fi].x * (1.0f / 512.0f);
    mu[fi] = m;
    iv[fi] = rsqrtf(st4[fi].y * (1.0f / 512.0f) - m * m + 1e-5f);
  }

  f32x4 aq[4][2] = {}, ak[4][2] = {}, av[4][2] = {};

  float4 rA[4][2], rB4[4][2], rg[2], rb[2], rg2[2], rb2[2];
#pragma unroll
  for (int fi = 0; fi < 4; fi++) {
    const float* hp = hR + (size_t)(RB[fi] + r16) * DM + q * 8;
    rA[fi][0] = *(const float4*)hp; rA[fi][1] = *(const float4*)(hp + 4);
  }
  rg[0] = *(const float4*)&lg[q * 8]; rg[1] = *(const float4*)&lg[q * 8 + 4];
  rb[0] = *(const float4*)&lb[q * 8]; rb[1] = *(const float4*)&lb[q * 8 + 4];
  // stage 0 was prefetched before entering the loop (pfA)

  for (int ks = 0; ks < 16; ks++) {
    if (ks + 1 < 16) {                  // A(ks+1): 12 vm-insts
      const int kb = (ks + 1) * 32 + q * 8;
#pragma unroll
      for (int fi = 0; fi < 4; fi++) {
        const float* hp = hR + (size_t)(RB[fi] + r16) * DM + kb;
        rB4[fi][0] = *(const float4*)hp; rB4[fi][1] = *(const float4*)(hp + 4);
      }
      rg2[0] = *(const float4*)&lg[kb]; rg2[1] = *(const float4*)&lg[kb + 4];
      rb2[0] = *(const float4*)&lb[kb]; rb2[1] = *(const float4*)&lb[kb + 4];
      __builtin_amdgcn_s_waitcnt(VM12);   // DMA(ks)+A(ks) done; A(ks+1) in flight
    } else {
      __builtin_amdgcn_s_waitcnt(VM0);
    }
    __builtin_amdgcn_s_barrier();
    if (ks + 1 < 16) {                  // DMA(ks+1) -> other buf (safe post-barrier)
      u16* nb = buf[(ks + 1) & 1];
#pragma unroll
      for (int z2 = 0; z2 < 6; z2++) dmaW32(wz[z2], 512, (ks + 1) * 32, nb + z2 * 2048, tid);
    }
    const u16* cb = buf[ks & 1];
    short8 ah[4], al[4];
#pragma unroll
    for (int fi = 0; fi < 4; fi++) {
      float v[8] = {
        (rA[fi][0].x - mu[fi]) * iv[fi] * rg[0].x + rb[0].x,
        (rA[fi][0].y - mu[fi]) * iv[fi] * rg[0].y + rb[0].y,
        (rA[fi][0].z - mu[fi]) * iv[fi] * rg[0].z + rb[0].z,
        (rA[fi][0].w - mu[fi]) * iv[fi] * rg[0].w + rb[0].w,
        (rA[fi][1].x - mu[fi]) * iv[fi] * rg[1].x + rb[1].x,
        (rA[fi][1].y - mu[fi]) * iv[fi] * rg[1].y + rb[1].y,
        (rA[fi][1].z - mu[fi]) * iv[fi] * rg[1].z + rb[1].z,
        (rA[fi][1].w - mu[fi]) * iv[fi] * rg[1].w + rb[1].w };
      split8(v, ah[fi], al[fi]);
    }
#pragma unroll
    for (int z = 0; z < 3; z++) {
      f32x4 (*ac)[2] = (z == 0) ? aq : ((z == 1) ? ak : av);
#pragma unroll
      for (int fj = 0; fj < 2; fj++) {
        const int n = wn + fj * 16 + r16;
        const int off = boff32(n, q);
        short8 bh = *(const short8*)&cb[(z * 2) * 2048 + off];
        short8 bl = *(const short8*)&cb[(z * 2 + 1) * 2048 + off];
#pragma unroll
        for (int fi = 0; fi < 4; fi++) {
          ac[fi][fj] = MFMA(ah[fi], bh, ac[fi][fj]);
          ac[fi][fj] = MFMA(ah[fi], bl, ac[fi][fj]);
          ac[fi][fj] = MFMA(al[fi], bh, ac[fi][fj]);
        }
      }
    }
#pragma unroll
    for (int fi = 0; fi < 4; fi++) { rA[fi][0] = rB4[fi][0]; rA[fi][1] = rB4[fi][1]; }
    rg[0] = rg2[0]; rg[1] = rg2[1]; rb[0] = rb2[0]; rb[1] = rb2[1];
  }
  __syncthreads();   // arena free for Q/K overlay

  u16 (*Qb)[66] = (u16(*)[66])sm;
  u16 (*Kb)[66] = (u16(*)[66])(sm + 16896);
  {
    const float* bq = a.bias6[0] + l * 512 + head * 64;
    const float* bk = a.bias6[1] + l * 512 + head * 64;
    const float* bv = a.bias6[2] + l * 512 + head * 64;
#pragma unroll
    for (int fi = 0; fi < 4; fi++) {
#pragma unroll
      for (int fj = 0; fj < 2; fj++) {
        const int col = wn + fj * 16 + r16;
        const int row0 = RB[fi] + q * 4;
        const float bqv = bq[col], bkv = bk[col], bvv = bv[col];
#pragma unroll
        for (int i = 0; i < 4; i++) {
          Qb[row0 + i][col] = f2bf(aq[fi][fj][i] + bqv);
          Kb[row0 + i][col] = f2bf(ak[fi][fj][i] + bkv);
          vT[(size_t)col * 128 + row0 + i] = f2bf(av[fi][fj][i] + bvv);
        }
      }
    }
  }
  __syncthreads();

  const int m0 = wave * 32;
  f32x4 sc[2][8] = {};
#pragma unroll
  for (int kk = 0; kk < 2; kk++) {
    short8 aQ[2];
#pragma unroll
    for (int fi = 0; fi < 2; fi++)
      aQ[fi] = *(const short8*)&Qb[m0 + fi * 16 + r16][kk * 32 + q * 8];
#pragma unroll
    for (int nt = 0; nt < 8; nt++) {
      short8 bK = *(const short8*)&Kb[nt * 16 + r16][kk * 32 + q * 8];
#pragma unroll
      for (int fi = 0; fi < 2; fi++) sc[fi][nt] = MFMA(aQ[fi], bK, sc[fi][nt]);
    }
  }
  __syncthreads();

#pragma unroll
  for (int fi = 0; fi < 2; fi++) {
#pragma unroll
    for (int i = 0; i < 4; i++) {
      float mrow = -1e30f;
#pragma unroll
      for (int nt = 0; nt < 8; nt++) {
        float v = sc[fi][nt][i] * 0.125f; sc[fi][nt][i] = v; mrow = fmaxf(mrow, v);
      }
#pragma unroll
      for (int o = 1; o < 16; o <<= 1) mrow = fmaxf(mrow, __shfl_xor(mrow, o, 64));
      float lsum = 0.f;
#pragma unroll
      for (int nt = 0; nt < 8; nt++) {
        float p = __expf(sc[fi][nt][i] - mrow); sc[fi][nt][i] = p; lsum += p;
      }
#pragma unroll
      for (int o = 1; o < 16; o <<= 1) lsum += __shfl_xor(lsum, o, 64);
      const float inv = 1.0f / lsum;
#pragma unroll
      for (int nt = 0; nt < 8; nt++) sc[fi][nt][i] *= inv;
    }
  }
  u16 (*Pb)[132] = (u16(*)[132])sm;
#pragma unroll
  for (int fi = 0; fi < 2; fi++)
#pragma unroll
    for (int nt = 0; nt < 8; nt++)
#pragma unroll
      for (int i = 0; i < 4; i++)
        Pb[m0 + fi * 16 + q * 4 + i][nt * 16 + r16] = f2bf(sc[fi][nt][i]);
  __syncthreads();

  f32x4 oa[2][4] = {};
#pragma unroll
  for (int kt = 0; kt < 4; kt++) {
    short8 aP[2];
#pragma unroll
    for (int fi = 0; fi < 2; fi++)
      aP[fi] = *(const short8*)&Pb[m0 + fi * 16 + r16][kt * 32 + q * 8];
#pragma unroll
    for (int nt = 0; nt < 4; nt++) {
      short8 bV = *(const short8*)(vT + (size_t)(nt * 16 + r16) * 128 + kt * 32 + q * 8);
#pragma unroll
      for (int fi = 0; fi < 2; fi++) oa[fi][nt] = MFMA(aP[fi], bV, oa[fi][nt]);
    }
  }
#pragma unroll
  for (int fi = 0; fi < 2; fi++)
#pragma unroll
    for (int nt = 0; nt < 4; nt++)
#pragma unroll
      for (int i = 0; i < 4; i++) {
        const int row = m0 + fi * 16 + q * 4 + i;
        const int col = head * 64 + nt * 16 + r16;
        float v = oa[fi][nt][i];
        u16 hv = f2bf(v);
        obh_g[(size_t)row * DM + col] = hv;
        obl_g[(size_t)row * DM + col] = f2bf(v - bf2f(hv));
      }
}

// ---------------------------------------------------------------------------
// tileBD: 64x64 split-bf16x3 GEMM, A pre-split from global, 3-deep ring DMA
// with vmcnt/s_barrier pipeline. Stages 0,1 prefetched in preceding barrier.
// ---------------------------------------------------------------------------
template<int EP>
__device__ void tileBD(const u16* Ahi, const u16* Alo, int K,
                       const u16* Whi, const u16* Wlo, const float* bias,
                       int bm, int bn, float* hIO, const float* Xx,
                       float* lnacc, char* sm, int tid)
{
  const int wave = tid >> 6, lane = tid & 63;
  const int q = lane >> 4, r16 = lane & 15;
  const int wm = (wave >> 1) * 32, wn = (wave & 1) * 32;
  const u16* bh0 = Whi + (size_t)bn * K;
  const u16* bl0 = Wlo + (size_t)bn * K;
  f32x4 acc[2][2] = {};
  const int nk = K >> 6;

  short8 cah[2][2], cal[2][2], nh[2][2], nl[2][2];
#pragma unroll
  for (int kk = 0; kk < 2; kk++)
#pragma unroll
    for (int fi = 0; fi < 2; fi++) {
      const size_t ao = (size_t)(bm + wm + fi * 16 + r16) * K + kk * 32 + q * 8;
      cah[kk][fi] = *(const short8*)(Ahi + ao);
      cal[kk][fi] = *(const short8*)(Alo + ao);
    }

  for (int ks = 0; ks < nk; ks++) {
    if (ks + 1 < nk) {                  // A(ks+1): 8 vm-insts
#pragma unroll
      for (int kk = 0; kk < 2; kk++)
#pragma unroll
        for (int fi = 0; fi < 2; fi++) {
          const size_t ao = (size_t)(bm + wm + fi * 16 + r16) * K + (ks + 1) * 64 + kk * 32 + q * 8;
          nh[kk][fi] = *(const short8*)(Ahi + ao);
          nl[kk][fi] = *(const short8*)(Alo + ao);
        }
      __builtin_amdgcn_s_waitcnt(VM12);   // allow A(ks+1)[8]+DMA(ks+1)[4]
    } else {
      __builtin_amdgcn_s_waitcnt(VM0);
    }
    __builtin_amdgcn_s_barrier();
    if (ks + 2 < nk) {                  // DMA(ks+2) -> slot (ks+2)%3
      u16* slot = (u16*)(sm + ((ks + 2) % 3) * 16384);
      dmaW64(bh0, K, (ks + 2) * 64, slot, tid);
      dmaW64(bl0, K, (ks + 2) * 64, slot + 4096, tid);
    }
    const u16* Bsh = (const u16*)(sm + (ks % 3) * 16384);
    const u16* Bsl = Bsh + 4096;
#pragma unroll
    for (int kk = 0; kk < 2; kk++) {
#pragma unroll
      for (int fj = 0; fj < 2; fj++) {
        const int n = wn + fj * 16 + r16;
        const int off = boff64(n, kk * 4 + q);
        short8 bh = *(const short8*)&Bsh[off];
        short8 bl = *(const short8*)&Bsl[off];
#pragma unroll
        for (int fi = 0; fi < 2; fi++) {
          acc[fi][fj] = MFMA(cah[kk][fi], bh, acc[fi][fj]);
          acc[fi][fj] = MFMA(cah[kk][fi], bl, acc[fi][fj]);
          acc[fi][fj] = MFMA(cal[kk][fi], bh, acc[fi][fj]);
        }
      }
    }
#pragma unroll
    for (int kk = 0; kk < 2; kk++)
#pragma unroll
      for (int fi = 0; fi < 2; fi++) { cah[kk][fi] = nh[kk][fi]; cal[kk][fi] = nl[kk][fi]; }
  }

  float outv[2][2][4];
#pragma unroll
  for (int fi = 0; fi < 2; fi++)
#pragma unroll
    for (int fj = 0; fj < 2; fj++) {
      const int col = bn + wn + fj * 16 + r16;
      const float bvv = bias[col];
      const int row0 = bm + wm + fi * 16 + q * 4;
#pragma unroll
      for (int i = 0; i < 4; i++) {
        const size_t off = (size_t)(row0 + i) * DM + col;
        if (EP == EP_RESID) {
          float hv = hIO[off] + acc[fi][fj][i] + bvv;
          hIO[off] = hv; outv[fi][fj][i] = hv;
        } else {
          float hv = hIO[off];
          float hn = 0.5f * hv + 0.5f * tanhf(hv + acc[fi][fj][i] + bvv + Xx[off]);
          hIO[off] = hn; outv[fi][fj][i] = hn;
        }
      }
    }
#pragma unroll
  for (int fi = 0; fi < 2; fi++)
#pragma unroll
    for (int i = 0; i < 4; i++) {
      float a0 = outv[fi][0][i], a1 = outv[fi][1][i];
      float s1 = a0 + a1, s2 = a0 * a0 + a1 * a1;
#pragma unroll
      for (int o = 1; o < 16; o <<= 1) { s1 += __shfl_xor(s1, o, 64); s2 += __shfl_xor(s2, o, 64); }
      if (r16 == 0) {
        const int row = bm + wm + fi * 16 + q * 4 + i;
        atomAddF(&lnacc[row * 2], s1);
        atomAddF(&lnacc[row * 2 + 1], s2);
      }
    }
}

// ---------------------------------------------------------------------------
// tileC2: LN2(atomic stats) + FFN1 + ReLU, two chained 64x64 tiles as one
// 16-stage ring-pipelined loop (weight base switches at stage 8).
// ---------------------------------------------------------------------------
__device__ void tileC2(const KArgs& a, int l, const float* h_g, const float* lnsrc,
                       u16* ffh_g, u16* ffl_g, int bm, int bn0, char* sm, int tid)
{
  const int wave = tid >> 6, lane = tid & 63;
  const int q = lane >> 4, r16 = lane & 15;
  const int wm = (wave >> 1) * 32, wn = (wave & 1) * 32;
  const size_t fOff = (size_t)l * 512 * 1024;
  const float* lg = a.ln2g + l * 512;
  const float* lb = a.ln2b + l * 512;

  // LN2 stats: atomic-written -> sc0sc1 read-through + explicit drain
  f32x2 stl[2];
#pragma unroll
  for (int fi = 0; fi < 2; fi++)
    stl[fi] = ldg_cs2(lnsrc + (bm + wm + fi * 16 + r16) * 2);
  vmwait0();

  float mu[2], iv[2];
#pragma unroll
  for (int fi = 0; fi < 2; fi++) {
    const float m = stl[fi].x * (1.0f / 512.0f);
    mu[fi] = m;
    iv[fi] = rsqrtf(stl[fi].y * (1.0f / 512.0f) - m * m + 1e-5f);
  }

  const u16* whB[2] = { a.WTh[4] + fOff + (size_t)bn0 * 512,
                        a.WTh[4] + fOff + (size_t)(bn0 + 512) * 512 };
  const u16* wlB[2] = { a.WTl[4] + fOff + (size_t)bn0 * 512,
                        a.WTl[4] + fOff + (size_t)(bn0 + 512) * 512 };
  const float* b1 = a.bias6[4] + l * 1024;
  f32x4 acc[2][2] = {};

  float4 rA[2][2][2], rB4[2][2][2], rg[2][2], rb[2][2], rg2[2][2], rb2[2][2];
#pragma unroll
  for (int kk = 0; kk < 2; kk++) {
    const int kb = kk * 32 + q * 8;
#pragma unroll
    for (int fi = 0; fi < 2; fi++) {
      const float* hp = h_g + (size_t)(bm + wm + fi * 16 + r16) * DM + kb;
      rA[kk][fi][0] = *(const float4*)hp; rA[kk][fi][1] = *(const float4*)(hp + 4);
    }
    rg[kk][0] = *(const float4*)&lg[kb]; rg[kk][1] = *(const float4*)&lg[kb + 4];
    rb[kk][0] = *(const float4*)&lb[kb]; rb[kk][1] = *(const float4*)&lb[kb + 4];
  }

  for (int s = 0; s < 16; s++) {
    if (s + 1 < 16) {                   // A(s+1): 16 vm-insts
      const int kb1 = ((s + 1) & 7) * 64;
#pragma unroll
      for (int kk = 0; kk < 2; kk++) {
        const int kb = kb1 + kk * 32 + q * 8;
#pragma unroll
        for (int fi = 0; fi < 2; fi++) {
          const float* hp = h_g + (size_t)(bm + wm + fi * 16 + r16) * DM + kb;
          rB4[kk][fi][0] = *(const float4*)hp; rB4[kk][fi][1] = *(const float4*)(hp + 4);
        }
        rg2[kk][0] = *(const float4*)&lg[kb]; rg2[kk][1] = *(const float4*)&lg[kb + 4];
        rb2[kk][0] = *(const float4*)&lb[kb]; rb2[kk][1] = *(const float4*)&lb[kb + 4];
      }
      __builtin_amdgcn_s_waitcnt(VM20);   // allow A(s+1)[16]+DMA(s+1)[4]
    } else {
      __builtin_amdgcn_s_waitcnt(VM0);
    }
    __builtin_amdgcn_s_barrier();
    if (s + 2 < 16) {
      const int t2 = (s + 2) >> 3, k2 = ((s + 2) & 7) * 64;
      u16* slot = (u16*)(sm + ((s + 2) % 3) * 16384);
      dmaW64(whB[t2], 512, k2, slot, tid);
      dmaW64(wlB[t2], 512, k2, slot + 4096, tid);
    }
    const u16* Bsh = (const u16*)(sm + (s % 3) * 16384);
    const u16* Bsl = Bsh + 4096;
#pragma unroll
    for (int kk = 0; kk < 2; kk++) {
      short8 ah[2], al[2];
#pragma unroll
      for (int fi = 0; fi < 2; fi++) {
        float v[8] = {
          (rA[kk][fi][0].x - mu[fi]) * iv[fi] * rg[kk][0].x + rb[kk][0].x,
          (rA[kk][fi][0].y - mu[fi]) * iv[fi] * rg[kk][0].y + rb[kk][0].y,
          (rA[kk][fi][0].z - mu[fi]) * iv[fi] * rg[kk][0].z + rb[kk][0].z,
          (rA[kk][fi][0].w - mu[fi]) * iv[fi] * rg[kk][0].w + rb[kk][0].w,
          (rA[kk][fi][1].x - mu[fi]) * iv[fi] * rg[kk][1].x + rb[kk][1].x,
          (rA[kk][fi][1].y - mu[fi]) * iv[fi] * rg[kk][1].y + rb[kk][1].y,
          (rA[kk][fi][1].z - mu[fi]) * iv[fi] * rg[kk][1].z + rb[kk][1].z,
          (rA[kk][fi][1].w - mu[fi]) * iv[fi] * rg[kk][1].w + rb[kk][1].w };
        split8(v, ah[fi], al[fi]);
      }
#pragma unroll
      for (int fj = 0; fj < 2; fj++) {
        const int n = wn + fj * 16 + r16;
        const int off = boff64(n, kk * 4 + q);
        short8 bh = *(const short8*)&Bsh[off];
        short8 bl = *(const short8*)&Bsl[off];
#pragma unroll
        for (int fi = 0; fi < 2; fi++) {
          acc[fi][fj] = MFMA(ah[fi], bh, acc[fi][fj]);
          acc[fi][fj] = MFMA(ah[fi], bl, acc[fi][fj]);
          acc[fi][fj] = MFMA(al[fi], bh, acc[fi][fj]);
        }
      }
    }
    if ((s & 7) == 7) {                 // tile (s>>3) epilogue
      const int t = s >> 3;
#pragma unroll
      for (int fi = 0; fi < 2; fi++)
#pragma unroll
        for (int fj = 0; fj < 2; fj++) {
          const int col = bn0 + t * 512 + wn + fj * 16 + r16;
          const float bvv = b1[col];
          const int row0 = bm + wm + fi * 16 + q * 4;
#pragma unroll
          for (int i = 0; i < 4; i++) {
            const size_t off = (size_t)(row0 + i) * 1024 + col;
            float r = fmaxf(acc[fi][fj][i] + bvv, 0.f);
            u16 hv = f2bf(r);
            ffh_g[off] = hv; ffl_g[off] = f2bf(r - bf2f(hv));
          }
          acc[fi][fj] = (f32x4){0.f, 0.f, 0.f, 0.f};
        }
    }
#pragma unroll
    for (int kk = 0; kk < 2; kk++) {
#pragma unroll
      for (int fi = 0; fi < 2; fi++) { rA[kk][fi][0] = rB4[kk][fi][0]; rA[kk][fi][1] = rB4[kk][fi][1]; }
      rg[kk][0] = rg2[kk][0]; rg[kk][1] = rg2[kk][1];
      rb[kk][0] = rb2[kk][0]; rb[kk][1] = rb2[kk][1];
    }
  }
}

// ---------------------------------------------------------------------------
__global__ __launch_bounds__(256, 1) void persist(KArgs a)
{
  __shared__ __align__(16) char smem[SMEM_BYTES];
  const int tid = threadIdx.x;
  const int bid = blockIdx.x;

  // publish this block's XCD id (normal store; flushed by the strong release)
  unsigned myxcd;
  asm volatile("s_getreg_b32 %0, hwreg(HW_REG_XCC_ID)" : "=s"(myxcd));
  myxcd &= 15u;
  if (tid == 0) a.bar[512 + bid] = myxcd;

  // ---- phase 0: weight split-transpose + embed + zero h + LN sums ----
  {
    float (*tile)[33] = (float (*)[33])smem;
    const int tx = tid & 31, ty = tid >> 5;
    for (int t = bid; t < 4096; t += NB) {
      int tensor, z, k0, n0, K, N;
      if (t < 2048)      { tensor = t >> 9;  int rem = t & 511;  z = rem >> 8; int r2 = rem & 255;
                           K = 512;  N = 512;  k0 = (r2 >> 4) << 5; n0 = (r2 & 15) << 5; }
      else if (t < 3072) { tensor = 4;       int rem = t - 2048; z = rem >> 9; int r2 = rem & 511;
                           K = 512;  N = 1024; k0 = (r2 >> 5) << 5; n0 = (r2 & 31) << 5; }
      else               { tensor = 5;       int rem = t - 3072; z = rem >> 9; int r2 = rem & 511;
                           K = 1024; N = 512;  k0 = (r2 >> 4) << 5; n0 = (r2 & 15) << 5; }
      const float* src = a.W[tensor]   + (size_t)z * K * N;
      u16* dhi         = a.WTh[tensor] + (size_t)z * K * N;
      u16* dlo         = a.WTl[tensor] + (size_t)z * K * N;
      __syncthreads();
#pragma unroll
      for (int r = 0; r < 4; r++) {
        int k = ty + r * 8;
        tile[k][tx] = src[(size_t)(k0 + k) * N + n0 + tx];
      }
      __syncthreads();
#pragma unroll
      for (int r = 0; r < 4; r++) {
        int n = ty + r * 8;
        float w = tile[tx][n];
        u16 hi = f2bf(w);
        dhi[(size_t)(n0 + n) * K + k0 + tx] = hi;
        dlo[(size_t)(n0 + n) * K + k0 + tx] = f2bf(w - bf2f(hi));
      }
    }
    for (int idx = bid * 256 + tid; idx < NTOK * DM; idx += NB * 256) {
      int t = idx >> 9, d = idx & 511, ss = t & 127;
      a.xe[idx] = a.tok[(size_t)a.x[t] * DM + d] + a.pos[ss * DM + d];
      a.h[idx] = 0.0f;
    }
    const int nstat = (41 + 40) * 8 * 256;
    for (int idx = bid * 256 + tid; idx < nstat; idx += NB * 256)
      a.ln1sum[idx] = 0.0f;
  }
  // one-time STRONG barrier (release+acquire)
  bar_arrive(a.bar + 256, tid);
  bar_wait(a.bar + 256, NB, tid);

  // ---- placement check + remap (uniform across all blocks) ----
  int grp, gb; bool fast;
  {
    int cnt[8] = {0, 0, 0, 0, 0, 0, 0, 0};
    int rank = 0; bool bad = false;
    for (int j = 0; j < 128; j++) {
      unsigned xj = a.bar[512 + j];
      if (xj > 7u) { bad = true; }
      else {
        cnt[xj]++;
        if (xj == myxcd && j < bid) rank++;
      }
    }
    fast = !bad;
    for (int x2 = 0; x2 < 8; x2++) fast = fast && (cnt[x2] == 16);
    if (fast) { grp = (int)myxcd; gb = rank; }           // group == XCD
    else      { grp = bid & 7;    gb = bid >> 3; }       // R0 mapping + fences
  }

  if (gb < 8) pfA(a, 0, gb, smem, tid);

  unsigned* gctr = a.bar + grp * 32;
  unsigned tgt = 0;
  const size_t r512  = (size_t)grp * 128 * 512;
  const size_t r1024 = (size_t)grp * 128 * 1024;
  float* h_g  = a.h  + r512;
  float* xe_g = a.xe + r512;
  u16 *obh_g = a.obh + r512, *obl_g = a.obl + r512;
  u16 *ffh_g = a.ffh + r1024, *ffl_g = a.ffl + r1024;
  const int bn = (gb & 7) * 64, bm = (gb >> 3) * 64;

  for (int it = 0; it < 40; it++) {
    const int l = it & 1;
    const size_t wOff = (size_t)l * 512 * 512;
    const size_t fOff = (size_t)l * 512 * 1024;
    float* ln1it = a.ln1sum + ((size_t)it * 8 + grp) * 256;
    float* ln2it = a.ln2sum + ((size_t)it * 8 + grp) * 256;
    float* ln1nx = a.ln1sum + ((size_t)(it + 1) * 8 + grp) * 256;

    if (gb < 8) phaseA(a, l, gb, grp, ln1it, h_g, obh_g, obl_g, smem, tid);
    g_arrive(fast, gctr, tid); tgt += 16;
    pfBD2(a.WTh[3] + wOff + (size_t)bn * 512, a.WTl[3] + wOff + (size_t)bn * 512, 512, smem, tid);
    g_wait(fast, gctr, tgt, tid);

    tileBD<EP_RESID>(obh_g, obl_g, 512, a.WTh[3] + wOff, a.WTl[3] + wOff,
                     a.bias6[3] + l * 512, bm, bn, h_g, nullptr, ln2it, smem, tid);
    g_arrive(fast, gctr, tid); tgt += 16;
    pfBD2(a.WTh[4] + fOff + (size_t)bn * 512, a.WTl[4] + fOff + (size_t)bn * 512, 512, smem, tid);
    g_wait(fast, gctr, tgt, tid);

    tileC2(a, l, h_g, ln2it, ffh_g, ffl_g, bm, bn, smem, tid);
    g_arrive(fast, gctr, tid); tgt += 16;
    pfBD2(a.WTh[5] + fOff + (size_t)bn * 1024, a.WTl[5] + fOff + (size_t)bn * 1024, 1024, smem, tid);
    g_wait(fast, gctr, tgt, tid);

    tileBD<EP_TANHLERP>(ffh_g, ffl_g, 1024, a.WTh[5] + fOff, a.WTl[5] + fOff,
                        a.bias6[5] + l * 512, bm, bn, h_g, xe_g, ln1nx, smem, tid);
    g_arrive(fast, gctr, tid); tgt += 16;
    if (it + 1 < 40 && gb < 8) pfA(a, (it + 1) & 1, gb, smem, tid);
    g_wait(fast, gctr, tgt, tid);
  }

  // group-local mean: hm[grp][512]
  {
    const int dim = gb * 32 + (tid >> 3);
    const int sub = tid & 7;
    float sv = 0.f;
    for (int si = sub; si < 128; si += 8) sv += h_g[(size_t)si * DM + dim];
    sv += __shfl_xor(sv, 1, 64); sv += __shfl_xor(sv, 2, 64); sv += __shfl_xor(sv, 4, 64);
    if (sub == 0) a.hm[grp * 512 + dim] = sv * (1.0f / 128.0f);
  }
  g_arrive(fast, gctr, tid); tgt += 16;
  g_wait(fast, gctr, tgt, tid);

  // group-local head: out[grp][1000]
  {
    const int idx = tid >> 2;
    const int n = gb * 63 + idx;
    const int sub = tid & 3;
    if (idx < 63 && n < 1000) {
      const float* hr = a.hm + grp * 512 + sub * 128;
      const float* wr = a.hw + (size_t)(sub * 128) * 1000 + n;
      float sv = 0.f;
      for (int j = 0; j < 128; j++) sv = fmaf(hr[j], wr[(size_t)j * 1000], sv);
      sv += __shfl_xor(sv, 1, 64);
      sv += __shfl_xor(sv, 2, 64);
      if (sub == 0) a.out[grp * 1000 + n] = sv + a.hb[n];
    }
  }
}

// ---------------------------------------------------------------------------
extern "C" void kernel_launch(void* const* d_in, const int* in_sizes, int n_in,
                              void* d_out, int out_size, void* d_ws, size_t ws_size,
                              hipStream_t stream)
{
  (void)in_sizes; (void)n_in; (void)out_size; (void)ws_size;
  KArgs a;
  a.x    = (const int*)d_in[0];
  a.tok  = (const float*)d_in[2];
  a.pos  = (const float*)d_in[3];
  a.W[0] = (const float*)d_in[4];   a.bias6[0] = (const float*)d_in[5];
  a.W[1] = (const float*)d_in[6];   a.bias6[1] = (const float*)d_in[7];
  a.W[2] = (const float*)d_in[8];   a.bias6[2] = (const float*)d_in[9];
  a.W[3] = (const float*)d_in[10];  a.bias6[3] = (const float*)d_in[11];
  a.W[4] = (const float*)d_in[12];  a.bias6[4] = (const float*)d_in[13];
  a.W[5] = (const float*)d_in[14];  a.bias6[5] = (const float*)d_in[15];
  a.ln1g = (const float*)d_in[16];
  a.ln1b = (const float*)d_in[17];
  a.ln2g = (const float*)d_in[18];
  a.ln2b = (const float*)d_in[19];
  a.hw   = (const float*)d_in[20];
  a.hb   = (const float*)d_in[21];
  a.out  = (float*)d_out;

  char* ws = (char*)d_ws;
  const size_t MB = 1ull << 20;
  a.xe   = (float*)(ws + 0 * MB);
  a.h    = (float*)(ws + 2 * MB);
  a.obh  = (u16*)(ws + 4 * MB);
  a.obl  = (u16*)(ws + 5 * MB);
  a.ffh  = (u16*)(ws + 6 * MB);
  a.ffl  = (u16*)(ws + 8 * MB);
  a.hm   = (float*)(ws + 10 * MB);
  a.vT   = (u16*)(ws + 11 * MB);
  a.WTh[0] = (u16*)(ws + 12 * MB);  a.WTl[0] = (u16*)(ws + 13 * MB);
  a.WTh[1] = (u16*)(ws + 14 * MB);  a.WTl[1] = (u16*)(ws + 15 * MB);
  a.WTh[2] = (u16*)(ws + 16 * MB);  a.WTl[2] = (u16*)(ws + 17 * MB);
  a.WTh[3] = (u16*)(ws + 18 * MB);  a.WTl[3] = (u16*)(ws + 19 * MB);
  a.WTh[4] = (u16*)(ws + 20 * MB);  a.WTl[4] = (u16*)(ws + 22 * MB);
  a.WTh[5] = (u16*)(ws + 24 * MB);  a.WTl[5] = (u16*)(ws + 26 * MB);
  a.bar    = (unsigned*)(ws + 28 * MB);
  a.ln1sum = (float*)(ws + 29 * MB);
  a.ln2sum = a.ln1sum + (size_t)41 * 8 * 256;

  bar_init<<<1, 256, 0, stream>>>(a.bar);
  persist<<<NB, 256, 0, stream>>>(a);
}